// Round 14
// baseline (1328.762 us; speedup 1.0000x reference)
//
#include <hip/hip_runtime.h>
#include <math.h>

#define Bsz 512
#define Tsz 512
#define Fin 32
#define Hd 64
#define CHUNK 32
#define NCH (Tsz / CHUNK)

typedef float f32x4 __attribute__((ext_vector_type(4)));
typedef _Float16 f16x8 __attribute__((ext_vector_type(8)));
typedef _Float16 f16x4 __attribute__((ext_vector_type(4)));

__device__ __forceinline__ float fsig(float x) {
    return __builtin_amdgcn_rcpf(1.0f + __expf(-x));
}
__device__ __forceinline__ float ftanh(float x) {
    return fmaf(2.0f, __builtin_amdgcn_rcpf(1.0f + __expf(-2.0f * x)), -1.0f);
}
__device__ __forceinline__ f32x4 MFMA(f16x8 a, f16x8 b, f32x4 c) {
    return __builtin_amdgcn_mfma_f32_16x16x32_f16(a, b, c, 0, 0, 0);
}

// ============================================================================
// R14: MFMA gates at the champion's geometry (grid 512, 256 thr, 2 blocks/CU,
// ONE barrier/step). Wave w owns W-row-tiles {w,4+w,8+w,12+w} = gates i,f,g,o
// for dims 16w..16w+15. A-frag = W rows (split f16, in regs, R13-verified
// layout: lane l -> A[l&15][8*(l>>4)+j]). B-frag = x_t / h_{t} REPLICATED
// over all 16 cols (B[k][c]=v[k]): every lane reads the same broadcast f16x8
// from LDS -> conflict-free. D (col=lane&15, row=4*(lane>>4)+reg, R13/m89-
// verified) then holds ALL FOUR GATES of dim d=16w+4*(l>>4)+reg in the same
// thread's accumulators: NO gate exchange, c/h update fully in-register
// (16x column redundancy, harmless). Per step: 8 broadcast LDS reads ->
// 36/48 MFMAs (~12-deep chains) -> 16 activations -> c,h -> one 8B h write
// -> barrier. Precision: R13's verified split-f16 (AhBh + AhBl + AlBh) for
// both weights and activations; h handoff carries (hi,lo) so the recurrence
// sees h to ~2^-22. c stays fp32 in registers.
// ============================================================================
template <int K, bool LAST>
__global__ __launch_bounds__(256, 2)
void lstm_mfma2(const float* __restrict__ X,      // [B,T,K]
                const float* __restrict__ Wih,    // [256,K]
                const float* __restrict__ Whh,    // [256,64]
                const float* __restrict__ bih,
                const float* __restrict__ bhh,
                float* __restrict__ hout,         // !LAST: h1 [B,T,64]
                const float* __restrict__ fcW,    // LAST only
                const float* __restrict__ fcb,
                float* __restrict__ out)
{
    constexpr int KS = K / 32;                 // x k-slices (1 or 2)
    __shared__ __align__(16) _Float16 xhi[2][CHUNK * K];
    __shared__ __align__(16) _Float16 xlo[2][CHUNK * K];
    __shared__ __align__(16) _Float16 hhi[2][Hd];
    __shared__ __align__(16) _Float16 hlo[2][Hd];
    __shared__ __align__(16) float hf32[Hd];

    const int tid = threadIdx.x;
    const int l   = tid & 63;
    const int w   = tid >> 6;                  // wave -> dims 16w..16w+15
    const int lr  = l & 15;                    // A row within tile / D col
    const int lg  = l >> 4;                    // k-group / D row block
    const int b   = blockIdx.x;

    // ---- A-fragments: W rows, split f16, registers (one-time load) ----
    f16x8 wiH[4][KS], wiL[4][KS], whH[4][2], whL[4][2];
    f32x4 bias[4];
#pragma unroll
    for (int g = 0; g < 4; ++g) {
        const int rbase = g * Hd + 16 * w;
#pragma unroll
        for (int ks = 0; ks < KS; ++ks) {
            f16x8 hi, lo;
#pragma unroll
            for (int j = 0; j < 8; ++j) {
                float v = Wih[(size_t)(rbase + lr) * K + ks * 32 + lg * 8 + j];
                _Float16 h16 = (_Float16)v;
                hi[j] = h16; lo[j] = (_Float16)(v - (float)h16);
            }
            wiH[g][ks] = hi; wiL[g][ks] = lo;
        }
#pragma unroll
        for (int ks = 0; ks < 2; ++ks) {
            f16x8 hi, lo;
#pragma unroll
            for (int j = 0; j < 8; ++j) {
                float v = Whh[(size_t)(rbase + lr) * Hd + ks * 32 + lg * 8 + j];
                _Float16 h16 = (_Float16)v;
                hi[j] = h16; lo[j] = (_Float16)(v - (float)h16);
            }
            whH[g][ks] = hi; whL[g][ks] = lo;
        }
#pragma unroll
        for (int r = 0; r < 4; ++r) {
            const int row = rbase + lg * 4 + r;        // D row mapping
            bias[g][r] = bih[row] + bhh[row];
        }
    }

    float c[4] = {0.f, 0.f, 0.f, 0.f};

    // ---- x staging: global f32 -> split f16 LDS (coalesced, 2-way-free) ----
    const float4* xg4 = (const float4*)(X + (size_t)b * Tsz * K);
    auto stagechunk = [&](int ci, int buf) {
        constexpr int NU = (CHUNK * K / 4) / 256;      // float4 per thread
#pragma unroll
        for (int u = 0; u < NU; ++u) {
            float4 v = xg4[(size_t)ci * (CHUNK * K / 4) + u * 256 + tid];
            const int e = (u * 256 + tid) * 4;         // f16 element index
            f16x4 hi, lo; _Float16 q;
            q = (_Float16)v.x; hi[0] = q; lo[0] = (_Float16)(v.x - (float)q);
            q = (_Float16)v.y; hi[1] = q; lo[1] = (_Float16)(v.y - (float)q);
            q = (_Float16)v.z; hi[2] = q; lo[2] = (_Float16)(v.z - (float)q);
            q = (_Float16)v.w; hi[3] = q; lo[3] = (_Float16)(v.w - (float)q);
            *(f16x4*)&xhi[buf][e] = hi;
            *(f16x4*)&xlo[buf][e] = lo;
        }
    };
    stagechunk(0, 0);
    if (tid < Hd) { hhi[0][tid] = (_Float16)0.f; hlo[0][tid] = (_Float16)0.f; }
    __syncthreads();

    float* hol = nullptr;
    if constexpr (!LAST) hol = hout + (size_t)b * Tsz * Hd;

#pragma unroll 1
    for (int t = 0; t < Tsz; ++t) {
        const int ci = t >> 5, cur = ci & 1, tt = t & 31, p = t & 1;
        if (tt == 0 && ci + 1 < NCH) stagechunk(ci + 1, cur ^ 1);

        // B-fragments: broadcast reads (replicated over cols)
        f16x8 xBh[KS], xBl[KS], hBh[2], hBl[2];
#pragma unroll
        for (int ks = 0; ks < KS; ++ks) {
            xBh[ks] = *(const f16x8*)&xhi[cur][tt * K + ks * 32 + lg * 8];
            xBl[ks] = *(const f16x8*)&xlo[cur][tt * K + ks * 32 + lg * 8];
        }
#pragma unroll
        for (int ks = 0; ks < 2; ++ks) {
            hBh[ks] = *(const f16x8*)&hhi[p][ks * 32 + lg * 8];
            hBl[ks] = *(const f16x8*)&hlo[p][ks * 32 + lg * 8];
        }

        // gates: acc[g] = bias + W_g·[x;h]   (split: AhBh + AhBl + AlBh)
        f32x4 aM[4], aE[4];
#pragma unroll
        for (int g = 0; g < 4; ++g) {
            aM[g] = bias[g];
            aE[g] = (f32x4){0.f, 0.f, 0.f, 0.f};
        }
#pragma unroll
        for (int ks = 0; ks < KS; ++ks)
#pragma unroll
            for (int g = 0; g < 4; ++g) {
                aM[g] = MFMA(wiH[g][ks], xBh[ks], aM[g]);
                aM[g] = MFMA(wiH[g][ks], xBl[ks], aM[g]);
                aE[g] = MFMA(wiL[g][ks], xBh[ks], aE[g]);
            }
#pragma unroll
        for (int ks = 0; ks < 2; ++ks)
#pragma unroll
            for (int g = 0; g < 4; ++g) {
                aM[g] = MFMA(whH[g][ks], hBh[ks], aM[g]);
                aM[g] = MFMA(whH[g][ks], hBl[ks], aM[g]);
                aE[g] = MFMA(whL[g][ks], hBh[ks], aE[g]);
            }

        // activations + c/h (all in-register; no gate exchange)
        float hv[4];
#pragma unroll
        for (int r = 0; r < 4; ++r) {
            float gi = fsig (aM[0][r] + aE[0][r]);
            float gf = fsig (aM[1][r] + aE[1][r]);
            float gg = ftanh(aM[2][r] + aE[2][r]);
            float go = fsig (aM[3][r] + aE[3][r]);
            c[r]  = fmaf(gf, c[r], gi * gg);
            hv[r] = go * ftanh(c[r]);
        }

        // h handoff: writer lanes (lr==0), 16 disjoint 8B slots -> no conflict
        if (lr == 0) {
            const int d0 = 16 * w + 4 * lg;
            f16x4 hi, lo; _Float16 q;
#pragma unroll
            for (int r = 0; r < 4; ++r) {
                q = (_Float16)hv[r];
                hi[r] = q; lo[r] = (_Float16)(hv[r] - (float)q);
            }
            *(f16x4*)&hhi[p ^ 1][d0] = hi;
            *(f16x4*)&hlo[p ^ 1][d0] = lo;
            if constexpr (!LAST) {
                *(float4*)&hol[(size_t)t * Hd + d0] =
                    (float4){hv[0], hv[1], hv[2], hv[3]};
            } else {
                if (t == Tsz - 1)
                    *(float4*)&hf32[d0] = (float4){hv[0], hv[1], hv[2], hv[3]};
            }
        }
        __syncthreads();   // the single per-step barrier (h visible)
    }

    if constexpr (LAST) {
        if (tid < 64) {
            float psum = hf32[tid] * fcW[tid];
#pragma unroll
            for (int off = 32; off > 0; off >>= 1)
                psum += __shfl_down(psum, off);
            if (tid == 0) out[b] = psum + fcb[0];
        }
    }
}

extern "C" void kernel_launch(void* const* d_in, const int* in_sizes, int n_in,
                              void* d_out, int out_size, void* d_ws, size_t ws_size,
                              hipStream_t stream)
{
    const float* x    = (const float*)d_in[0];
    const float* Wih0 = (const float*)d_in[1];
    const float* Whh0 = (const float*)d_in[2];
    const float* bih0 = (const float*)d_in[3];
    const float* bhh0 = (const float*)d_in[4];
    const float* Wih1 = (const float*)d_in[5];
    const float* Whh1 = (const float*)d_in[6];
    const float* bih1 = (const float*)d_in[7];
    const float* bhh1 = (const float*)d_in[8];
    const float* fcW  = (const float*)d_in[9];
    const float* fcb  = (const float*)d_in[10];
    float* out = (float*)d_out;
    float* h1  = (float*)d_ws;   // B*T*H fp32 = 67.1 MB (known to fit)

    lstm_mfma2<Fin, false><<<dim3(Bsz), dim3(256), 0, stream>>>(
        x, Wih0, Whh0, bih0, bhh0, h1, nullptr, nullptr, nullptr);
    lstm_mfma2<Hd, true><<<dim3(Bsz), dim3(256), 0, stream>>>(
        h1, Wih1, Whh1, bih1, bhh1, nullptr, fcW, fcb, out);
}

// Round 16
// 756.044 us; speedup vs baseline: 1.7575x; 1.7575x over previous
//
#include <hip/hip_runtime.h>
#include <math.h>

#define Bsz 512
#define Tsz 512
#define Fin 32
#define Hd 64
#define BB 16
#define NBLK (Bsz / BB)   // 32 blocks

typedef float f32x4 __attribute__((ext_vector_type(4)));
typedef _Float16 f16x8 __attribute__((ext_vector_type(8)));
typedef _Float16 f16x4 __attribute__((ext_vector_type(4)));

__device__ __forceinline__ float fsig(float x) {
    return __builtin_amdgcn_rcpf(1.0f + __expf(-x));
}
__device__ __forceinline__ float ftanh(float x) {
    return fmaf(2.0f, __builtin_amdgcn_rcpf(1.0f + __expf(-2.0f * x)), -1.0f);
}
__device__ __forceinline__ f32x4 MFMA(f16x8 a, f16x8 b, f32x4 c) {
    return __builtin_amdgcn_mfma_f32_16x16x32_f16(a, b, c, 0, 0, 0);
}
// NOTE: returns via scalar temps — references cannot bind to ext_vector
// elements (R15 compile failure).
__device__ __forceinline__ void fsplit(float v, _Float16& hi, _Float16& lo) {
    hi = (_Float16)v; lo = (_Float16)(v - (float)hi);
}

// ============================================================================
// R16 = R15 with the vector-element reference binding fixed (scalar temps).
// Fused 2-layer MFMA LSTM, 16 batches/block, grid 32, 512 thr, 1 bar/step.
// A = W-tile (A[row=l&15][k=8*(l>>4)+j], split f16, in regs, R13-verified).
// B = inputs with cols = 16 REAL batches (slab [k>>3][b][j]). D[row=gaterow]
// [col=batch] (m89/R13-verified) -> wave w4 owning tiles {g*4+w4} gives each
// thread ALL 4 GATES of (batch=l&15, dims 16*w4+4*lg+r): c/h update fully
// in-register, NO gate exchange (R14-verified trick, zero col redundancy).
// Waves 0-3 = layer0 step s; waves 4-7 = layer1 step s-1; h1 via a 4-slot
// LDS ring in B-slab layout (never HBM). Split-f16 (WhXh + WhXl + WlXh).
// ============================================================================
__global__ __launch_bounds__(512, 1)
void lstm_fused(const float* __restrict__ X,
                const float* __restrict__ Wih0, const float* __restrict__ Whh0,
                const float* __restrict__ bih0, const float* __restrict__ bhh0,
                const float* __restrict__ Wih1, const float* __restrict__ Whh1,
                const float* __restrict__ bih1, const float* __restrict__ bhh1,
                const float* __restrict__ fcW, const float* __restrict__ fcb,
                float* __restrict__ out)
{
    __shared__ __align__(16) _Float16 x0h[2][8][4][16][8];  // x slabs (16 KB)
    __shared__ __align__(16) _Float16 x0l[2][8][4][16][8];  // (16 KB)
    __shared__ __align__(16) _Float16 r0h[4][8][16][8];     // h0 ring (8 KB)
    __shared__ __align__(16) _Float16 r0l[4][8][16][8];     // (8 KB)
    __shared__ __align__(16) _Float16 h1h[2][8][16][8];     // L1 own h (4 KB)
    __shared__ __align__(16) _Float16 h1l[2][8][16][8];     // (4 KB)
    __shared__ float fcbuf[16][16];

    const int tid = threadIdx.x;
    const int l   = tid & 63;
    const int wv  = tid >> 6;
    const int wvu = __builtin_amdgcn_readfirstlane(wv);
    const int lr  = l & 15;          // A row / D col(batch)
    const int lg  = l >> 4;          // k-group / D row block
    const int w4  = wvu & 3;         // dim-slice 16*w4..16*w4+15
    const bool isL1 = (wvu >= 4);
    const int b0  = blockIdx.x * BB;

    // ---- A-fragments: weights, split f16, one-time load ----
    f16x8 AxH[4][2], AxL[4][2], AhH[4][2], AhL[4][2];
    f32x4 bias4[4];
    {
        const float* Wih = isL1 ? Wih1 : Wih0;
        const float* Whh = isL1 ? Whh1 : Whh0;
        const float* bih = isL1 ? bih1 : bih0;
        const float* bhh = isL1 ? bhh1 : bhh0;
        const int K   = isL1 ? Hd : Fin;
        const int KSx = isL1 ? 2 : 1;
#pragma unroll
        for (int g = 0; g < 4; ++g) {
            const int rbase = g * Hd + 16 * w4;
            for (int ks = 0; ks < KSx; ++ks) {
                f16x8 hi, lo;
#pragma unroll
                for (int j = 0; j < 8; ++j) {
                    _Float16 th, tl;
                    fsplit(Wih[(size_t)(rbase + lr) * K + ks * 32 + lg * 8 + j],
                           th, tl);
                    hi[j] = th; lo[j] = tl;
                }
                AxH[g][ks] = hi; AxL[g][ks] = lo;
            }
#pragma unroll
            for (int ks = 0; ks < 2; ++ks) {
                f16x8 hi, lo;
#pragma unroll
                for (int j = 0; j < 8; ++j) {
                    _Float16 th, tl;
                    fsplit(Whh[(size_t)(rbase + lr) * Hd + ks * 32 + lg * 8 + j],
                           th, tl);
                    hi[j] = th; lo[j] = tl;
                }
                AhH[g][ks] = hi; AhL[g][ks] = lo;
            }
            f32x4 bb;
#pragma unroll
            for (int r = 0; r < 4; ++r)
                bb[r] = bih[rbase + 4 * lg + r] + bhh[rbase + 4 * lg + r];
            bias4[g] = bb;
        }
    }

    float c[4]  = {0.f, 0.f, 0.f, 0.f};
    float hv[4] = {0.f, 0.f, 0.f, 0.f};

    const float4* Xg4 = (const float4*)X;
    float4 pf[4];
    // x prefetch (L0 waves, tid<256): group = 8 steps x 16 b x 32 k = 1024 f4
    auto pload = [&](int g) {
#pragma unroll
        for (int i = 0; i < 4; ++i) {
            const int idx = i * 256 + tid;
            const int bl = idx >> 6, tt = (idx >> 3) & 7, m = idx & 7;
            pf[i] = Xg4[((size_t)(b0 + bl) * Tsz + g * 8 + tt) * 8 + m];
        }
    };
    auto stage = [&](int buf) {
#pragma unroll
        for (int i = 0; i < 4; ++i) {
            const int idx = i * 256 + tid;
            const int bl = idx >> 6, tt = (idx >> 3) & 7, m = idx & 7;
            float4 v = pf[i];
            f16x4 hi, lo;
            _Float16 th, tl;
            fsplit(v.x, th, tl); hi[0] = th; lo[0] = tl;
            fsplit(v.y, th, tl); hi[1] = th; lo[1] = tl;
            fsplit(v.z, th, tl); hi[2] = th; lo[2] = tl;
            fsplit(v.w, th, tl); hi[3] = th; lo[3] = tl;
            *(f16x4*)&x0h[buf][tt][m >> 1][bl][4 * (m & 1)] = hi;
            *(f16x4*)&x0l[buf][tt][m >> 1][bl][4 * (m & 1)] = lo;
        }
    };

    // prologue: stage group 0; zero ring slot 3 and h1[0]
    if (!isL1) { pload(0); stage(0); }
    if (tid < 256) {
        ((f16x4*)&r0h[3][0][0][0])[tid] = (f16x4){0, 0, 0, 0};
        ((f16x4*)&r0l[3][0][0][0])[tid] = (f16x4){0, 0, 0, 0};
    } else {
        ((f16x4*)&h1h[0][0][0][0])[tid - 256] = (f16x4){0, 0, 0, 0};
        ((f16x4*)&h1l[0][0][0][0])[tid - 256] = (f16x4){0, 0, 0, 0};
    }
    __syncthreads();

#pragma unroll 1
    for (int s = 0; s <= Tsz; ++s) {
        if (!isL1) {
            if (s < Tsz) {
                const int g = s >> 3;
                if ((s & 7) == 0 && g + 1 < 64) pload(g + 1);
                const int buf = g & 1, st = s & 7, slot = (s - 1) & 3;
                f32x4 aM[4];
#pragma unroll
                for (int gg = 0; gg < 4; ++gg) aM[gg] = bias4[gg];
                {   // x contribution (K=32, one slice)
                    f16x8 Bh = *(const f16x8*)&x0h[buf][st][lg][lr][0];
                    f16x8 Bl = *(const f16x8*)&x0l[buf][st][lg][lr][0];
#pragma unroll
                    for (int gg = 0; gg < 4; ++gg) {
                        aM[gg] = MFMA(AxH[gg][0], Bh, aM[gg]);
                        aM[gg] = MFMA(AxH[gg][0], Bl, aM[gg]);
                        aM[gg] = MFMA(AxL[gg][0], Bh, aM[gg]);
                    }
                }
#pragma unroll
                for (int ks = 0; ks < 2; ++ks) {   // h contribution
                    f16x8 Bh = *(const f16x8*)&r0h[slot][4 * ks + lg][lr][0];
                    f16x8 Bl = *(const f16x8*)&r0l[slot][4 * ks + lg][lr][0];
#pragma unroll
                    for (int gg = 0; gg < 4; ++gg) {
                        aM[gg] = MFMA(AhH[gg][ks], Bh, aM[gg]);
                        aM[gg] = MFMA(AhH[gg][ks], Bl, aM[gg]);
                        aM[gg] = MFMA(AhL[gg][ks], Bh, aM[gg]);
                    }
                }
#pragma unroll
                for (int r = 0; r < 4; ++r) {
                    float gi = fsig(aM[0][r]);
                    float gf = fsig(aM[1][r]);
                    float gt = ftanh(aM[2][r]);
                    float go = fsig(aM[3][r]);
                    c[r]  = fmaf(gf, c[r], gi * gt);
                    hv[r] = go * ftanh(c[r]);
                }
                const int kg = 2 * w4 + (lg >> 1), j0 = 4 * (lg & 1);
                f16x4 hi, lo;
#pragma unroll
                for (int r = 0; r < 4; ++r) {
                    _Float16 th, tl;
                    fsplit(hv[r], th, tl);
                    hi[r] = th; lo[r] = tl;
                }
                *(f16x4*)&r0h[s & 3][kg][lr][j0] = hi;
                *(f16x4*)&r0l[s & 3][kg][lr][j0] = lo;
                if ((s & 7) == 7 && g + 1 < 64) stage((g + 1) & 1);
            }
        } else {
            if (s >= 1) {
                const int t = s - 1;
                const int slot = t & 3, p = t & 1;
                f32x4 aM[4];
#pragma unroll
                for (int gg = 0; gg < 4; ++gg) aM[gg] = bias4[gg];
#pragma unroll
                for (int ks = 0; ks < 2; ++ks) {   // x = h1[t] from ring
                    f16x8 Bh = *(const f16x8*)&r0h[slot][4 * ks + lg][lr][0];
                    f16x8 Bl = *(const f16x8*)&r0l[slot][4 * ks + lg][lr][0];
#pragma unroll
                    for (int gg = 0; gg < 4; ++gg) {
                        aM[gg] = MFMA(AxH[gg][ks], Bh, aM[gg]);
                        aM[gg] = MFMA(AxH[gg][ks], Bl, aM[gg]);
                        aM[gg] = MFMA(AxL[gg][ks], Bh, aM[gg]);
                    }
                }
#pragma unroll
                for (int ks = 0; ks < 2; ++ks) {   // own h
                    f16x8 Bh = *(const f16x8*)&h1h[p][4 * ks + lg][lr][0];
                    f16x8 Bl = *(const f16x8*)&h1l[p][4 * ks + lg][lr][0];
#pragma unroll
                    for (int gg = 0; gg < 4; ++gg) {
                        aM[gg] = MFMA(AhH[gg][ks], Bh, aM[gg]);
                        aM[gg] = MFMA(AhH[gg][ks], Bl, aM[gg]);
                        aM[gg] = MFMA(AhL[gg][ks], Bh, aM[gg]);
                    }
                }
#pragma unroll
                for (int r = 0; r < 4; ++r) {
                    float gi = fsig(aM[0][r]);
                    float gf = fsig(aM[1][r]);
                    float gt = ftanh(aM[2][r]);
                    float go = fsig(aM[3][r]);
                    c[r]  = fmaf(gf, c[r], gi * gt);
                    hv[r] = go * ftanh(c[r]);
                }
                const int kg = 2 * w4 + (lg >> 1), j0 = 4 * (lg & 1);
                f16x4 hi, lo;
#pragma unroll
                for (int r = 0; r < 4; ++r) {
                    _Float16 th, tl;
                    fsplit(hv[r], th, tl);
                    hi[r] = th; lo[r] = tl;
                }
                *(f16x4*)&h1h[p ^ 1][kg][lr][j0] = hi;
                *(f16x4*)&h1l[p ^ 1][kg][lr][j0] = lo;
            }
        }
        __syncthreads();   // the single per-superstep barrier
    }

    // fused FC: L1 threads hold h2[b=lr, d=16*w4+4*lg+r] for t=511
    if (isL1) {
        float ps = 0.f;
#pragma unroll
        for (int r = 0; r < 4; ++r)
            ps += hv[r] * fcW[16 * w4 + 4 * lg + r];
        fcbuf[lr][w4 * 4 + lg] = ps;
    }
    __syncthreads();
    if (tid < 16) {
        float s = fcb[0];
#pragma unroll
        for (int j = 0; j < 16; ++j) s += fcbuf[tid][j];
        out[b0 + tid] = s;
    }
}

extern "C" void kernel_launch(void* const* d_in, const int* in_sizes, int n_in,
                              void* d_out, int out_size, void* d_ws, size_t ws_size,
                              hipStream_t stream)
{
    const float* x    = (const float*)d_in[0];
    const float* Wih0 = (const float*)d_in[1];
    const float* Whh0 = (const float*)d_in[2];
    const float* bih0 = (const float*)d_in[3];
    const float* bhh0 = (const float*)d_in[4];
    const float* Wih1 = (const float*)d_in[5];
    const float* Whh1 = (const float*)d_in[6];
    const float* bih1 = (const float*)d_in[7];
    const float* bhh1 = (const float*)d_in[8];
    const float* fcW  = (const float*)d_in[9];
    const float* fcb  = (const float*)d_in[10];
    float* out = (float*)d_out;
    (void)d_ws; (void)ws_size;   // h1 never leaves LDS: no workspace

    lstm_fused<<<dim3(NBLK), dim3(512), 0, stream>>>(
        x, Wih0, Whh0, bih0, bhh0, Wih1, Whh1, bih1, bhh1, fcW, fcb, out);
}